// Round 6
// baseline (150.072 us; speedup 1.0000x reference)
//
#include <hip/hip_runtime.h>
#include <math.h>

// Problem constants: N=8, S=8192, C=1, K=1024, V=64
#define NS   65536
#define KK   1024
#define VV   64
#define SPW  64               // samples per wave (1-wave blocks)
#define NB   (NS / SPW)       // 1024 blocks -> 1 wave/SIMD, 4 blocks/CU
#define CHC  128              // codes per LDS chunk (16 KB)
#define NCHK (KK / CHC)       // 8 chunks
#define TPC  (CHC / 16)       // 8 MFMA tiles per chunk

// Output layout (flat, return order):
#define OUT0_OFF 0            // (8,8192,1,64) = 4,194,304
#define OUT1_OFF 4194304
#define OUT2_OFF 4259840
#define ENT_OFF  4325376      // entropy scalar; doubles as completion counter

// ws layout: [0,4K) hist u32; [4K,8K) enorm f32; [8K,8K+128K) bf16 codebook [1024][64]

typedef __attribute__((ext_vector_type(8))) short bf16x8;
typedef __attribute__((ext_vector_type(4))) float f32x4;

__device__ __forceinline__ short f2bf(float f) {
    unsigned u = __float_as_uint(f);
    u = (u + 0x7fffu + ((u >> 16) & 1u)) >> 16;   // RNE
    return (short)u;
}

__global__ void vq_prep(const float* __restrict__ emb, unsigned int* __restrict__ hist,
                        float* __restrict__ enorm, short* __restrict__ cb,
                        unsigned int* __restrict__ entCnt) {
    int t = blockIdx.x * blockDim.x + threadIdx.x;   // 1024 threads, one code each
    if (t == 0) entCnt[0] = 0u;
    if (t < KK) {
        hist[t] = 0u;
        const float4* e4 = (const float4*)(emb + (size_t)t * VV);
        float s = 0.f;
        union { short sh[8]; bf16x8 v; } pk;
        bf16x8* dst = (bf16x8*)(cb + (size_t)t * VV);
        #pragma unroll
        for (int i = 0; i < 8; ++i) {
            float4 f0 = e4[2 * i], f1 = e4[2 * i + 1];
            s = fmaf(f0.x, f0.x, s); s = fmaf(f0.y, f0.y, s);
            s = fmaf(f0.z, f0.z, s); s = fmaf(f0.w, f0.w, s);
            s = fmaf(f1.x, f1.x, s); s = fmaf(f1.y, f1.y, s);
            s = fmaf(f1.z, f1.z, s); s = fmaf(f1.w, f1.w, s);
            pk.sh[0] = f2bf(f0.x); pk.sh[1] = f2bf(f0.y);
            pk.sh[2] = f2bf(f0.z); pk.sh[3] = f2bf(f0.w);
            pk.sh[4] = f2bf(f1.x); pk.sh[5] = f2bf(f1.y);
            pk.sh[6] = f2bf(f1.z); pk.sh[7] = f2bf(f1.w);
            dst[i] = pk.v;
        }
        enorm[t] = s;
    }
}

__global__ __launch_bounds__(64, 1) void vq_main(
    const float* __restrict__ x, const float* __restrict__ emb,
    const float* __restrict__ enorm, const short* __restrict__ cb,
    unsigned int* __restrict__ hist,
    float* __restrict__ out0, float* __restrict__ out1, float* __restrict__ out2,
    float* __restrict__ entOut)
{
    // XOR-swizzled codebook chunk: granule g (16B) of code c at c*128 + (g^(c&7))*16
    __shared__ __align__(16) char  sCB[CHC * 128];   // 16 KB
    __shared__ __align__(8)  float sEN[CHC];
    __shared__ int sBest[SPW];
    __shared__ unsigned sLast;

    const int lane = threadIdx.x;      // one wave per block
    const int col  = lane & 15;        // code-within-tile
    const int quad = lane >> 4;        // k-granule group
    const int c7   = col & 7;
    const int l3   = lane >> 3;        // staging: code-within-octet
    const int l7   = lane & 7;         // staging: granule
    const int samp0 = blockIdx.x * SPW;

    // ---- A fragments: 4 m-tiles x 2 k-halves (verified 16x16x32 layout) ----
    bf16x8 a[8];
    #pragma unroll
    for (int mt = 0; mt < 4; ++mt) {
        const float* xp = x + (size_t)(samp0 + mt * 16 + col) * VV + quad * 8;
        float4 p0 = *(const float4*)(xp);
        float4 p1 = *(const float4*)(xp + 4);
        float4 p2 = *(const float4*)(xp + 32);
        float4 p3 = *(const float4*)(xp + 36);
        bf16x8 lo, hi;
        lo[0]=f2bf(p0.x); lo[1]=f2bf(p0.y); lo[2]=f2bf(p0.z); lo[3]=f2bf(p0.w);
        lo[4]=f2bf(p1.x); lo[5]=f2bf(p1.y); lo[6]=f2bf(p1.z); lo[7]=f2bf(p1.w);
        hi[0]=f2bf(p2.x); hi[1]=f2bf(p2.y); hi[2]=f2bf(p2.z); hi[3]=f2bf(p2.w);
        hi[4]=f2bf(p3.x); hi[5]=f2bf(p3.y); hi[6]=f2bf(p3.z); hi[7]=f2bf(p3.w);
        a[2 * mt] = lo; a[2 * mt + 1] = hi;
    }

    // ---- stage chunk 0 (coalesced global; swizzled LDS write) ----
    char* const wb = sCB + l3 * 128 + ((l7 ^ l3) << 4);   // per-lane constant
    {
        const float4* g = (const float4*)cb;
        float2 pe = ((const float2*)enorm)[lane];
        #pragma unroll
        for (int i = 0; i < 16; ++i) *(float4*)(wb + i * 1024) = g[i * 64 + lane];
        *(float2*)&sEN[2 * lane] = pe;
    }
    __syncthreads();

    float bs[16];
    int   bt[16];
    #pragma unroll
    for (int j = 0; j < 16; ++j) { bs[j] = -INFINITY; bt[j] = 0; }

    const char* const rb0 = sCB + col * 128 + ((quad ^ c7) << 4);
    const char* const rb1 = sCB + col * 128 + (((4 + quad) ^ c7) << 4);

    for (int ch = 0; ch < NCHK; ++ch) {
        // issue next chunk's global loads into registers (hidden under compute)
        float4 pf[16]; float2 pe;
        const bool has = (ch + 1) < NCHK;
        if (has) {
            const float4* g = (const float4*)(cb + (size_t)(ch + 1) * CHC * VV);
            #pragma unroll
            for (int i = 0; i < 16; ++i) pf[i] = g[i * 64 + lane];
            pe = ((const float2*)(enorm + (ch + 1) * CHC))[lane];
        }

        #pragma unroll
        for (int tl = 0; tl < TPC; ++tl) {
            bf16x8 b0 = *(const bf16x8*)(rb0 + tl * 2048);
            bf16x8 b1 = *(const bf16x8*)(rb1 + tl * 2048);
            float en = sEN[tl * 16 + col];
            float ci = -0.5f * en;
            f32x4 cv = {ci, ci, ci, ci};
            const int code = ch * CHC + tl * 16 + col;
            #pragma unroll
            for (int mt = 0; mt < 4; ++mt) {
                f32x4 acc = __builtin_amdgcn_mfma_f32_16x16x32_bf16(a[2 * mt],     b0, cv,  0, 0, 0);
                acc       = __builtin_amdgcn_mfma_f32_16x16x32_bf16(a[2 * mt + 1], b1, acc, 0, 0, 0);
                #pragma unroll
                for (int r = 0; r < 4; ++r) {
                    bool g0 = acc[r] > bs[mt * 4 + r];     // strict > : first max kept
                    bs[mt * 4 + r] = g0 ? acc[r] : bs[mt * 4 + r];
                    bt[mt * 4 + r] = g0 ? code : bt[mt * 4 + r];
                }
            }
        }

        if (has) {
            __syncthreads();   // 1-wave block: cheap lgkmcnt drain before overwrite
            #pragma unroll
            for (int i = 0; i < 16; ++i) *(float4*)(wb + i * 1024) = pf[i];
            *(float2*)&sEN[2 * lane] = pe;
            __syncthreads();
        }
    }

    // ---- reduce argmax over the 16 col-lanes of each quad group ----
    #pragma unroll
    for (int off = 1; off < 16; off <<= 1) {
        #pragma unroll
        for (int j = 0; j < 16; ++j) {
            float os = __shfl_xor(bs[j], off, 64);
            int   oc = __shfl_xor(bt[j], off, 64);
            bool take = (os > bs[j]) || (os == bs[j] && oc < bt[j]);
            bs[j] = take ? os : bs[j];
            bt[j] = take ? oc : bt[j];
        }
    }
    if (col == 0) {
        #pragma unroll
        for (int mt = 0; mt < 4; ++mt)
            #pragma unroll
            for (int r = 0; r < 4; ++r)
                sBest[mt * 16 + quad * 4 + r] = bt[mt * 4 + r];
    }
    __syncthreads();

    // ---- exact fp32 d^2 epilogue (one lane per sample) ----
    {
        const int n = samp0 + lane;
        const int best = sBest[lane];
        const float4* xp4 = (const float4*)(x   + (size_t)n    * VV);
        const float4* ep4 = (const float4*)(emb + (size_t)best * VV);
        float d = 0.f;
        #pragma unroll
        for (int i = 0; i < 16; ++i) {
            float4 xv = xp4[i], ev = ep4[i];
            float t0 = xv.x - ev.x, t1 = xv.y - ev.y, t2 = xv.z - ev.z, t3 = xv.w - ev.w;
            d = fmaf(t0, t0, d); d = fmaf(t1, t1, d);
            d = fmaf(t2, t2, d); d = fmaf(t3, t3, d);
        }
        out1[n] = d;
        out2[n] = d;
        atomicAdd(&hist[best], 1u);
    }

    // ---- coalesced out0 gather-write: lane pair covers a 128B half-row ----
    #pragma unroll
    for (int h = 0; h < 2; ++h) {
        const int smp  = h * 32 + (lane >> 1);
        const int half = lane & 1;
        const int best = sBest[smp];
        const float4* src = (const float4*)(emb + (size_t)best * VV + half * 32);
        float4*       dst = (float4*)(out0 + (size_t)(samp0 + smp) * VV + half * 32);
        #pragma unroll
        for (int i = 0; i < 8; ++i) dst[i] = src[i];
    }

    // ---- completion counter + fused entropy in the last block ----
    __builtin_amdgcn_s_waitcnt(0);   // drain this wave's hist atomics
    unsigned int* entCnt = (unsigned int*)entOut;
    if (lane == 0) sLast = (atomicAdd(entCnt, 1u) == (NB - 1)) ? 1u : 0u;
    __syncthreads();
    if (sLast) {
        float e = 0.f;
        #pragma unroll
        for (int i = 0; i < 16; ++i) {
            unsigned c = atomicAdd(&hist[i * 64 + lane], 0u);   // coherent read
            if (c) { float p = (float)c * (1.0f / (float)NS); e -= p * logf(p); }
        }
        #pragma unroll
        for (int off = 32; off > 0; off >>= 1) e += __shfl_down(e, off, 64);
        if (lane == 0) entOut[0] = e;
    }
}

extern "C" void kernel_launch(void* const* d_in, const int* in_sizes, int n_in,
                              void* d_out, int out_size, void* d_ws, size_t ws_size,
                              hipStream_t stream) {
    const float* x   = (const float*)d_in[0];   // (8,8192,1,64) fp32
    const float* emb = (const float*)d_in[1];   // (1,1024,64) fp32
    float* out = (float*)d_out;
    unsigned int* hist  = (unsigned int*)d_ws;
    float*        enorm = (float*)((char*)d_ws + 4096);
    short*        cb    = (short*)((char*)d_ws + 8192);   // bf16 codebook, 128 KB

    vq_prep<<<16, 64, 0, stream>>>(emb, hist, enorm, cb, (unsigned int*)(out + ENT_OFF));
    vq_main<<<NB, 64, 0, stream>>>(x, emb, enorm, cb, hist,
                                   out + OUT0_OFF, out + OUT1_OFF, out + OUT2_OFF,
                                   out + ENT_OFF);
}

// Round 7
// 109.709 us; speedup vs baseline: 1.3679x; 1.3679x over previous
//
#include <hip/hip_runtime.h>
#include <math.h>

// Problem constants: N=8, S=8192, C=1, K=1024, V=64
#define NS   65536
#define KK   1024
#define VV   64
#define SPB  128              // samples per block (4 waves x 32)
#define NB   (NS / SPB)       // 512 blocks -> 2 blocks/CU, 8 waves/CU
#define CHC  128              // codes per LDS chunk (16 KB)
#define NCHK (KK / CHC)       // 8 chunks
#define TPC  (CHC / 16)       // 8 MFMA tiles per chunk

// Output layout (flat, return order):
#define OUT0_OFF 0            // (8,8192,1,64) = 4,194,304
#define OUT1_OFF 4194304
#define OUT2_OFF 4259840
#define ENT_OFF  4325376      // entropy scalar; doubles as completion counter

// ws layout: [0,4K) hist u32; [4K,8K) cinit f32 (=1-0.5|e|^2); [8K,136K) bf16 codebook

typedef __attribute__((ext_vector_type(8))) short bf16x8;
typedef __attribute__((ext_vector_type(4))) float f32x4;

__device__ __forceinline__ short f2bf(float f) {
    unsigned u = __float_as_uint(f);
    u = (u + 0x7fffu + ((u >> 16) & 1u)) >> 16;   // RNE
    return (short)u;
}

__global__ void vq_prep(const float* __restrict__ emb, unsigned int* __restrict__ hist,
                        float* __restrict__ cinit, short* __restrict__ cb,
                        unsigned int* __restrict__ entCnt) {
    int t = blockIdx.x * blockDim.x + threadIdx.x;   // 1024 threads, one code each
    if (t == 0) entCnt[0] = 0u;
    if (t < KK) {
        hist[t] = 0u;
        const float4* e4 = (const float4*)(emb + (size_t)t * VV);
        float s = 0.f;
        union { short sh[8]; bf16x8 v; } pk;
        bf16x8* dst = (bf16x8*)(cb + (size_t)t * VV);   // linear layout
        #pragma unroll
        for (int i = 0; i < 8; ++i) {
            float4 f0 = e4[2 * i], f1 = e4[2 * i + 1];
            s = fmaf(f0.x, f0.x, s); s = fmaf(f0.y, f0.y, s);
            s = fmaf(f0.z, f0.z, s); s = fmaf(f0.w, f0.w, s);
            s = fmaf(f1.x, f1.x, s); s = fmaf(f1.y, f1.y, s);
            s = fmaf(f1.z, f1.z, s); s = fmaf(f1.w, f1.w, s);
            pk.sh[0] = f2bf(f0.x); pk.sh[1] = f2bf(f0.y);
            pk.sh[2] = f2bf(f0.z); pk.sh[3] = f2bf(f0.w);
            pk.sh[4] = f2bf(f1.x); pk.sh[5] = f2bf(f1.y);
            pk.sh[6] = f2bf(f1.z); pk.sh[7] = f2bf(f1.w);
            dst[i] = pk.v;
        }
        cinit[t] = 1.0f - 0.5f * s;   // MFMA C-init; keeps scores in (0.85,1.15)
    }
}

__global__ __launch_bounds__(256, 2) void vq_main(
    const float* __restrict__ x, const float* __restrict__ emb,
    const float* __restrict__ cinit, const short* __restrict__ cb,
    unsigned int* __restrict__ hist,
    float* __restrict__ out0, float* __restrict__ out1, float* __restrict__ out2,
    float* __restrict__ entOut)
{
    // Swizzled chunk layout: granule g (16B) of code c at c*128 + ((g^(c&7))<<4)
    __shared__ __align__(16) char  sCB[2][CHC * 128];   // 2 x 16 KB
    __shared__ __align__(16) float sCI[KK];             // 4 KB (all C-inits)
    __shared__ unsigned sPk[SPB];
    __shared__ float    sXn[SPB];
    __shared__ float    sPart[4];
    __shared__ unsigned sLast;

    const int tid  = threadIdx.x;
    const int lane = tid & 63;
    const int wv   = tid >> 6;
    const int col  = lane & 15;     // code-within-tile / A-row m
    const int quad = lane >> 4;     // k-granule group
    const int samp0 = blockIdx.x * SPB;
    const int wbase = wv * 32;      // wave's 32 samples within block

    // ---- A fragments (2 m-tiles) + fp32 |x|^2 per sample ----
    bf16x8 a[4];
    float  xn[2];
    #pragma unroll
    for (int mt = 0; mt < 2; ++mt) {
        const float* xp = x + (size_t)(samp0 + wbase + mt * 16 + col) * VV + quad * 8;
        float4 p0 = *(const float4*)(xp);
        float4 p1 = *(const float4*)(xp + 4);
        float4 p2 = *(const float4*)(xp + 32);
        float4 p3 = *(const float4*)(xp + 36);
        bf16x8 lo, hi;
        lo[0]=f2bf(p0.x); lo[1]=f2bf(p0.y); lo[2]=f2bf(p0.z); lo[3]=f2bf(p0.w);
        lo[4]=f2bf(p1.x); lo[5]=f2bf(p1.y); lo[6]=f2bf(p1.z); lo[7]=f2bf(p1.w);
        hi[0]=f2bf(p2.x); hi[1]=f2bf(p2.y); hi[2]=f2bf(p2.z); hi[3]=f2bf(p2.w);
        hi[4]=f2bf(p3.x); hi[5]=f2bf(p3.y); hi[6]=f2bf(p3.z); hi[7]=f2bf(p3.w);
        a[2 * mt] = lo; a[2 * mt + 1] = hi;
        float s = 0.f;
        s=fmaf(p0.x,p0.x,s); s=fmaf(p0.y,p0.y,s); s=fmaf(p0.z,p0.z,s); s=fmaf(p0.w,p0.w,s);
        s=fmaf(p1.x,p1.x,s); s=fmaf(p1.y,p1.y,s); s=fmaf(p1.z,p1.z,s); s=fmaf(p1.w,p1.w,s);
        s=fmaf(p2.x,p2.x,s); s=fmaf(p2.y,p2.y,s); s=fmaf(p2.z,p2.z,s); s=fmaf(p2.w,p2.w,s);
        s=fmaf(p3.x,p3.x,s); s=fmaf(p3.y,p3.y,s); s=fmaf(p3.z,p3.z,s); s=fmaf(p3.w,p3.w,s);
        xn[mt] = s;
    }
    #pragma unroll
    for (int mt = 0; mt < 2; ++mt) {     // reduce |x|^2 over the 4 k-quads
        xn[mt] += __shfl_xor(xn[mt], 16, 64);
        xn[mt] += __shfl_xor(xn[mt], 32, 64);
    }

    // ---- stage all C-inits + chunk 0 (swizzled; 4 granules/thread) ----
    ((float4*)sCI)[tid] = ((const float4*)cinit)[tid];
    int woff[4];
    #pragma unroll
    for (int i = 0; i < 4; ++i) {
        int gid = i * 256 + tid;
        int c = gid >> 3, g = gid & 7;
        woff[i] = c * 128 + ((g ^ (c & 7)) << 4);
    }
    {
        const float4* g0 = (const float4*)cb;
        #pragma unroll
        for (int i = 0; i < 4; ++i)
            *(float4*)(sCB[0] + woff[i]) = g0[i * 256 + tid];
    }
    __syncthreads();

    // packed running maxima: high 22 bits = score (positive fp32), low 10 = 1023-code
    unsigned pm[8];
    #pragma unroll
    for (int j = 0; j < 8; ++j) pm[j] = 0u;

    const int rb0off = col * 128 + ((quad ^ (col & 7)) << 4);        // granule quad
    const int rb1off = col * 128 + (((4 + quad) ^ (col & 7)) << 4);  // granule 4+quad
    const unsigned invc = 1023u - (unsigned)col;

    for (int ch = 0; ch < NCHK; ++ch) {
        float4 pf[4];
        if (ch < NCHK - 1) {             // prefetch next chunk (16 transient VGPRs)
            const float4* g = (const float4*)(cb + (size_t)(ch + 1) * CHC * VV);
            #pragma unroll
            for (int i = 0; i < 4; ++i) pf[i] = g[i * 256 + tid];
        }
        const char* B = sCB[ch & 1];
        const unsigned invch = invc - (unsigned)(ch * CHC);
        #pragma unroll
        for (int tl = 0; tl < TPC; ++tl) {
            bf16x8 b0 = *(const bf16x8*)(B + tl * 2048 + rb0off);
            bf16x8 b1 = *(const bf16x8*)(B + tl * 2048 + rb1off);
            float ci = sCI[ch * CHC + tl * 16 + col];
            f32x4 cv = {ci, ci, ci, ci};
            const unsigned inv = invch - (unsigned)(tl * 16);
            #pragma unroll
            for (int mt = 0; mt < 2; ++mt) {
                f32x4 acc = __builtin_amdgcn_mfma_f32_16x16x32_bf16(a[2*mt],     b0, cv,  0, 0, 0);
                acc       = __builtin_amdgcn_mfma_f32_16x16x32_bf16(a[2*mt + 1], b1, acc, 0, 0, 0);
                #pragma unroll
                for (int r = 0; r < 4; ++r) {
                    unsigned pk2 = (__float_as_uint(acc[r]) & 0xFFFFFC00u) | inv;  // v_and_or_b32
                    pm[mt*4+r] = (pk2 > pm[mt*4+r]) ? pk2 : pm[mt*4+r];            // v_max_u32
                }
            }
        }
        if (ch < NCHK - 1) {
            char* dstB = sCB[(ch + 1) & 1];
            #pragma unroll
            for (int i = 0; i < 4; ++i) *(float4*)(dstB + woff[i]) = pf[i];
        }
        __syncthreads();
    }

    // ---- reduce packed maxima over the 16 cols of each quad group ----
    #pragma unroll
    for (int off = 1; off < 16; off <<= 1) {
        #pragma unroll
        for (int j = 0; j < 8; ++j) {
            unsigned o = (unsigned)__shfl_xor((int)pm[j], off, 64);
            pm[j] = (o > pm[j]) ? o : pm[j];
        }
    }
    if (col == 0) {
        #pragma unroll
        for (int mt = 0; mt < 2; ++mt)
            #pragma unroll
            for (int r = 0; r < 4; ++r)
                sPk[wbase + mt * 16 + quad * 4 + r] = pm[mt * 4 + r];  // D row = quad*4+r
    }
    if (quad == 0) {
        #pragma unroll
        for (int mt = 0; mt < 2; ++mt) sXn[wbase + mt * 16 + col] = xn[mt];
    }
    __syncthreads();

    // ---- epilogue: d^2 = |x|^2 - 2(score-1);  score = 1 + x.e - 0.5|e|^2 ----
    if (tid < SPB) {
        unsigned p = sPk[tid];
        int   code = 1023 - (int)(p & 1023u);
        float sf   = __uint_as_float(p & 0xFFFFFC00u);
        float d    = fmaf(-2.f, sf - 1.0f, sXn[tid]);   // sf-1 exact (Sterbenz)
        int n = samp0 + tid;
        out1[n] = d;
        out2[n] = d;
        atomicAdd(&hist[code], 1u);
    }
    {   // coalesced out0 gather-write: lane pair covers one 256B sample row
        const int smp  = tid >> 1;
        const int half = tid & 1;
        const int code = 1023 - (int)(sPk[smp] & 1023u);
        const float4* src = (const float4*)(emb + (size_t)code * VV + half * 32);
        float4*       dst = (float4*)(out0 + (size_t)(samp0 + smp) * VV + half * 32);
        #pragma unroll
        for (int i = 0; i < 8; ++i) dst[i] = src[i];
    }

    // ---- completion counter + fused entropy in the last block ----
    __syncthreads();   // per-wave vmcnt(0) drain before barrier => hist atomics visible
    unsigned int* entCnt = (unsigned int*)entOut;
    if (tid == 0) sLast = (atomicAdd(entCnt, 1u) == (NB - 1)) ? 1u : 0u;
    __syncthreads();
    if (sLast) {
        float e = 0.f;
        #pragma unroll
        for (int i = 0; i < 4; ++i) {
            unsigned c = atomicAdd(&hist[i * 256 + tid], 0u);   // coherent read
            if (c) { float p = (float)c * (1.0f / (float)NS); e -= p * logf(p); }
        }
        #pragma unroll
        for (int off = 32; off > 0; off >>= 1) e += __shfl_down(e, off, 64);
        if (lane == 0) sPart[wv] = e;
        __syncthreads();
        if (tid == 0) entOut[0] = sPart[0] + sPart[1] + sPart[2] + sPart[3];
    }
}

extern "C" void kernel_launch(void* const* d_in, const int* in_sizes, int n_in,
                              void* d_out, int out_size, void* d_ws, size_t ws_size,
                              hipStream_t stream) {
    const float* x   = (const float*)d_in[0];   // (8,8192,1,64) fp32
    const float* emb = (const float*)d_in[1];   // (1,1024,64) fp32
    float* out = (float*)d_out;
    unsigned int* hist  = (unsigned int*)d_ws;
    float*        cinit = (float*)((char*)d_ws + 4096);
    short*        cb    = (short*)((char*)d_ws + 8192);   // bf16 codebook, 128 KB

    vq_prep<<<4, 256, 0, stream>>>(emb, hist, cinit, cb, (unsigned int*)(out + ENT_OFF));
    vq_main<<<NB, 256, 0, stream>>>(x, emb, cinit, cb, hist,
                                    out + OUT0_OFF, out + OUT1_OFF, out + OUT2_OFF,
                                    out + ENT_OFF);
}

// Round 8
// 101.320 us; speedup vs baseline: 1.4812x; 1.0828x over previous
//
#include <hip/hip_runtime.h>
#include <math.h>

// Problem constants: N=8, S=8192, C=1, K=1024, V=64
#define NS   65536
#define KK   1024
#define VV   64
#define SPB  128              // samples per block (4 waves x 32)
#define NB   (NS / SPB)       // 512 blocks -> 2 blocks/CU, 8 waves/CU
#define CHC  256              // codes per LDS chunk (32 KB)
#define NCHK (KK / CHC)       // 4 chunks
#define TPC  (CHC / 16)       // 16 MFMA tiles per chunk
#define CHB  (CHC * VV * 2)   // chunk bytes (32768)

// Output layout (flat, return order):
#define OUT0_OFF 0            // (8,8192,1,64) = 4,194,304
#define OUT1_OFF 4194304
#define OUT2_OFF 4259840
#define ENT_OFF  4325376      // entropy scalar; doubles as completion counter

// ws layout: [0,4K) hist u32; [4K,8K) cinit f32 (=1-0.5|e|^2); [8K,136K) swizzled bf16 codebook

typedef __attribute__((ext_vector_type(8))) short bf16x8;
typedef __attribute__((ext_vector_type(4))) float f32x4;

// async global->LDS 16B DMA: LDS dst = wave-uniform base + lane*16
#define ASYNC16(gp, lp) __builtin_amdgcn_global_load_lds(                      \
    (const __attribute__((address_space(1))) unsigned int*)(gp),               \
    (__attribute__((address_space(3))) unsigned int*)(lp), 16, 0, 0)

__device__ __forceinline__ short f2bf(float f) {
    unsigned u = __float_as_uint(f);
    u = (u + 0x7fffu + ((u >> 16) & 1u)) >> 16;   // RNE
    return (short)u;
}

__global__ void vq_prep(const float* __restrict__ emb, unsigned int* __restrict__ hist,
                        float* __restrict__ cinit, short* __restrict__ cb,
                        unsigned int* __restrict__ entCnt) {
    int t = blockIdx.x * blockDim.x + threadIdx.x;   // 1024 threads, one code each
    if (t == 0) entCnt[0] = 0u;
    if (t < KK) {
        hist[t] = 0u;
        const float4* e4 = (const float4*)(emb + (size_t)t * VV);
        const int ch = t >> 8, cw = t & 255;
        short* base = cb + (size_t)ch * (CHC * VV) + cw * 64;   // code block (8 granules)
        float s = 0.f;
        union { short sh[8]; bf16x8 v; } pk;
        #pragma unroll
        for (int g = 0; g < 8; ++g) {
            float4 f0 = e4[2 * g], f1 = e4[2 * g + 1];
            s = fmaf(f0.x, f0.x, s); s = fmaf(f0.y, f0.y, s);
            s = fmaf(f0.z, f0.z, s); s = fmaf(f0.w, f0.w, s);
            s = fmaf(f1.x, f1.x, s); s = fmaf(f1.y, f1.y, s);
            s = fmaf(f1.z, f1.z, s); s = fmaf(f1.w, f1.w, s);
            pk.sh[0] = f2bf(f0.x); pk.sh[1] = f2bf(f0.y);
            pk.sh[2] = f2bf(f0.z); pk.sh[3] = f2bf(f0.w);
            pk.sh[4] = f2bf(f1.x); pk.sh[5] = f2bf(f1.y);
            pk.sh[6] = f2bf(f1.z); pk.sh[7] = f2bf(f1.w);
            // swizzled granule slot: g ^ (cw&7)  -> LDS-linear staging lands conflict-free
            *(bf16x8*)(base + ((g ^ (cw & 7)) * 8)) = pk.v;
        }
        cinit[t] = 1.0f - 0.5f * s;   // MFMA C-init; keeps scores in (0.85,1.15)
    }
}

__global__ __launch_bounds__(256, 2) void vq_main(
    const float* __restrict__ x, const float* __restrict__ emb,
    const float* __restrict__ cinit, const short* __restrict__ cb,
    unsigned int* __restrict__ hist,
    float* __restrict__ out0, float* __restrict__ out1, float* __restrict__ out2,
    float* __restrict__ entOut)
{
    __shared__ __align__(16) char  sCB[2][CHB];   // 2 x 32 KB, swizzled chunks
    __shared__ __align__(16) float sCI[KK];       // 4 KB
    __shared__ unsigned sPk[SPB];
    __shared__ float    sXn[SPB];
    __shared__ float    sPart[4];
    __shared__ unsigned sLast;

    const int tid  = threadIdx.x;
    const int lane = tid & 63;
    const int wv   = tid >> 6;
    const int col  = lane & 15;     // code-within-tile / A-row m
    const int quad = lane >> 4;     // k-granule group
    const int samp0 = blockIdx.x * SPB;
    const int wbase = wv * 32;      // wave's 32 samples within block

    // ---- kick off async staging of chunk 0 (no VGPR round-trip) ----
    {
        const char* g0 = (const char*)cb;
        #pragma unroll
        for (int i = 0; i < 8; ++i) {
            const int off = (i * 256 + tid) * 16;
            ASYNC16(g0 + off, sCB[0] + off);
        }
        ((float4*)sCI)[tid] = ((const float4*)cinit)[tid];
    }

    // ---- A fragments (2 m-tiles) + fp32 |x|^2 per sample (covers staging latency) ----
    bf16x8 a[4];
    float  xn[2];
    #pragma unroll
    for (int mt = 0; mt < 2; ++mt) {
        const float* xp = x + (size_t)(samp0 + wbase + mt * 16 + col) * VV + quad * 8;
        float4 p0 = *(const float4*)(xp);
        float4 p1 = *(const float4*)(xp + 4);
        float4 p2 = *(const float4*)(xp + 32);
        float4 p3 = *(const float4*)(xp + 36);
        bf16x8 lo, hi;
        lo[0]=f2bf(p0.x); lo[1]=f2bf(p0.y); lo[2]=f2bf(p0.z); lo[3]=f2bf(p0.w);
        lo[4]=f2bf(p1.x); lo[5]=f2bf(p1.y); lo[6]=f2bf(p1.z); lo[7]=f2bf(p1.w);
        hi[0]=f2bf(p2.x); hi[1]=f2bf(p2.y); hi[2]=f2bf(p2.z); hi[3]=f2bf(p2.w);
        hi[4]=f2bf(p3.x); hi[5]=f2bf(p3.y); hi[6]=f2bf(p3.z); hi[7]=f2bf(p3.w);
        a[2 * mt] = lo; a[2 * mt + 1] = hi;
        float s = 0.f;
        s=fmaf(p0.x,p0.x,s); s=fmaf(p0.y,p0.y,s); s=fmaf(p0.z,p0.z,s); s=fmaf(p0.w,p0.w,s);
        s=fmaf(p1.x,p1.x,s); s=fmaf(p1.y,p1.y,s); s=fmaf(p1.z,p1.z,s); s=fmaf(p1.w,p1.w,s);
        s=fmaf(p2.x,p2.x,s); s=fmaf(p2.y,p2.y,s); s=fmaf(p2.z,p2.z,s); s=fmaf(p2.w,p2.w,s);
        s=fmaf(p3.x,p3.x,s); s=fmaf(p3.y,p3.y,s); s=fmaf(p3.z,p3.z,s); s=fmaf(p3.w,p3.w,s);
        xn[mt] = s;
    }
    #pragma unroll
    for (int mt = 0; mt < 2; ++mt) {     // reduce |x|^2 over the 4 k-quads
        xn[mt] += __shfl_xor(xn[mt], 16, 64);
        xn[mt] += __shfl_xor(xn[mt], 32, 64);
    }
    __syncthreads();   // chunk-0 DMA + sCI visible (latency covered by A-frag work)

    // packed running maxima: high 22 bits = score (positive fp32), low 10 = 1023-code
    unsigned pm[8];
    #pragma unroll
    for (int j = 0; j < 8; ++j) pm[j] = 0u;

    const int rb0off = col * 128 + ((quad ^ (col & 7)) << 4);
    const int rb1off = col * 128 + (((4 + quad) ^ (col & 7)) << 4);
    const unsigned invc = 1023u - (unsigned)col;

    for (int ch = 0; ch < NCHK; ++ch) {
        if (ch + 1 < NCHK) {            // async prefetch next chunk (~1000 cyc in flight)
            const char* g = (const char*)cb + (size_t)(ch + 1) * CHB;
            char* nb = sCB[(ch + 1) & 1];
            #pragma unroll
            for (int i = 0; i < 8; ++i) {
                const int off = (i * 256 + tid) * 16;
                ASYNC16(g + off, nb + off);
            }
        }
        const char* B = sCB[ch & 1];
        const unsigned invch = invc - (unsigned)(ch * CHC);
        unsigned pkp[8];
        #pragma unroll
        for (int tl = 0; tl < TPC; ++tl) {
            bf16x8 b0 = *(const bf16x8*)(B + tl * 2048 + rb0off);
            bf16x8 b1 = *(const bf16x8*)(B + tl * 2048 + rb1off);
            float ci = sCI[ch * CHC + tl * 16 + col];
            f32x4 cv = {ci, ci, ci, ci};
            const unsigned inv = invch - (unsigned)(tl * 16);
            unsigned pk2[8];
            #pragma unroll
            for (int mt = 0; mt < 2; ++mt) {
                f32x4 acc = __builtin_amdgcn_mfma_f32_16x16x32_bf16(a[2*mt],     b0, cv,  0, 0, 0);
                acc       = __builtin_amdgcn_mfma_f32_16x16x32_bf16(a[2*mt + 1], b1, acc, 0, 0, 0);
                #pragma unroll
                for (int r = 0; r < 4; ++r)
                    pk2[mt*4+r] = (__float_as_uint(acc[r]) & 0xFFFFFC00u) | inv;  // v_and_or_b32
            }
            if (tl & 1) {
                #pragma unroll
                for (int j = 0; j < 8; ++j) {      // v_max3_u32
                    unsigned t2 = pkp[j] > pk2[j] ? pkp[j] : pk2[j];
                    pm[j] = pm[j] > t2 ? pm[j] : t2;
                }
            } else {
                #pragma unroll
                for (int j = 0; j < 8; ++j) pkp[j] = pk2[j];
            }
        }
        __syncthreads();   // drains next-chunk DMA (already landed) + buffer handoff
    }

    // ---- reduce packed maxima over the 16 cols of each quad group ----
    #pragma unroll
    for (int off = 1; off < 16; off <<= 1) {
        #pragma unroll
        for (int j = 0; j < 8; ++j) {
            unsigned o = (unsigned)__shfl_xor((int)pm[j], off, 64);
            pm[j] = (o > pm[j]) ? o : pm[j];
        }
    }
    if (col == 0) {
        #pragma unroll
        for (int mt = 0; mt < 2; ++mt)
            #pragma unroll
            for (int r = 0; r < 4; ++r)
                sPk[wbase + mt * 16 + quad * 4 + r] = pm[mt * 4 + r];  // D row = quad*4+r
    }
    if (quad == 0) {
        #pragma unroll
        for (int mt = 0; mt < 2; ++mt) sXn[wbase + mt * 16 + col] = xn[mt];
    }
    __syncthreads();

    // ---- epilogue: d^2 = |x|^2 - 2(score-1);  score = 1 + x.e - 0.5|e|^2 ----
    if (tid < SPB) {
        unsigned p = sPk[tid];
        int   code = 1023 - (int)(p & 1023u);
        float sf   = __uint_as_float(p & 0xFFFFFC00u);
        float d    = fmaf(-2.f, sf - 1.0f, sXn[tid]);   // sf-1 exact (Sterbenz)
        int n = samp0 + tid;
        out1[n] = d;
        out2[n] = d;
        atomicAdd(&hist[code], 1u);
    }
    {   // coalesced out0 gather-write: lane pair covers one 256B sample row
        const int smp  = tid >> 1;
        const int half = tid & 1;
        const int code = 1023 - (int)(sPk[smp] & 1023u);
        const float4* src = (const float4*)(emb + (size_t)code * VV + half * 32);
        float4*       dst = (float4*)(out0 + (size_t)(samp0 + smp) * VV + half * 32);
        #pragma unroll
        for (int i = 0; i < 8; ++i) dst[i] = src[i];
    }

    // ---- completion counter + fused entropy in the last block ----
    __syncthreads();   // vmcnt(0) drain => this block's hist atomics are globally visible
    unsigned int* entCnt = (unsigned int*)entOut;
    if (tid == 0) sLast = (atomicAdd(entCnt, 1u) == (NB - 1)) ? 1u : 0u;
    __syncthreads();
    if (sLast) {
        float e = 0.f;
        #pragma unroll
        for (int i = 0; i < 4; ++i) {
            unsigned c = atomicAdd(&hist[i * 256 + tid], 0u);   // coherent read
            if (c) { float p = (float)c * (1.0f / (float)NS); e -= p * logf(p); }
        }
        #pragma unroll
        for (int off = 32; off > 0; off >>= 1) e += __shfl_down(e, off, 64);
        if (lane == 0) sPart[wv] = e;
        __syncthreads();
        if (tid == 0) entOut[0] = sPart[0] + sPart[1] + sPart[2] + sPart[3];
    }
}

extern "C" void kernel_launch(void* const* d_in, const int* in_sizes, int n_in,
                              void* d_out, int out_size, void* d_ws, size_t ws_size,
                              hipStream_t stream) {
    const float* x   = (const float*)d_in[0];   // (8,8192,1,64) fp32
    const float* emb = (const float*)d_in[1];   // (1,1024,64) fp32
    float* out = (float*)d_out;
    unsigned int* hist  = (unsigned int*)d_ws;
    float*        cinit = (float*)((char*)d_ws + 4096);
    short*        cb    = (short*)((char*)d_ws + 8192);   // swizzled bf16 codebook, 128 KB

    vq_prep<<<4, 256, 0, stream>>>(emb, hist, cinit, cb, (unsigned int*)(out + ENT_OFF));
    vq_main<<<NB, 256, 0, stream>>>(x, emb, cinit, cb, hist,
                                    out + OUT0_OFF, out + OUT1_OFF, out + OUT2_OFF,
                                    out + ENT_OFF);
}